// Round 10
// baseline (171.332 us; speedup 1.0000x reference)
//
#include <hip/hip_runtime.h>
#include <math.h>

// CLUB_NCE: N=512, D=400, H=400.  Three dispatches: memset + K1 + K2.
// LAW (R5-R9): these kernels are latency-bound; >=3.25 waves/SIMD required,
// and loads must be prefetched into registers so compute overlaps vmem.
// K1 : hidden GEMMs, 416 blocks x 512 thr (3.25 waves/SIMD). 64n x 32h tile,
//      2x2/thread, k-split 2; [k][row] LDS; k-halves combined via fp32
//      atomicAdd (2 addends -> commutative -> bit-exact) into zeroed buffers.
//      mat0 -> hxT8[h/8][j][h%8] (oct layout), mat1 -> hyb[n][h] (+b1 in kh0).
// K2 : pair scores, grid (8 jx, 128 ig) x 256 thr = 4096 waves (4/SIMD).
//      wave = (grp: 2 i-rows, half: 200 h). B = 2 coalesced dwordx4/group
//      from hxT8 with register prefetch of group g+1; A rows + W2 staged in
//      LDS (broadcast b128 reads). Halves combine via LDS; fused softplus +
//      per-row fp64 wave reduction; last block (atomic counter) finishes.

#define NSAMP 512
#define DIM 400
#define HID 400

// ---------------- K1 ----------------
// b: mat = b&1, kh = (b>>1)&1, r = b>>2 (0..103): nt = r&7 (8), ht = r>>3 (0..12)
__global__ __launch_bounds__(512) void club_gemm_kernel(
    const float* __restrict__ X, const float* __restrict__ Y,
    const float* __restrict__ W1, const float* __restrict__ b1,
    float* __restrict__ hxT8, float* __restrict__ hyb,
    unsigned int* __restrict__ counter)
{
    __shared__ __align__(16) float As[100 * 64];   // [k][n] 25.6 KB
    __shared__ __align__(16) float Bs[100 * 32];   // [k][h] 12.8 KB
    const int t = threadIdx.x;
    const int b = blockIdx.x;
    if (b == 0 && t == 0) *counter = 0u;
    const int tx = t & 15;          // h-pair
    const int ty = t >> 4;          // n-pair (0..31)

    const int mat = b & 1, kh = (b >> 1) & 1, r = b >> 2;
    const int n0 = (r & 7) * 64, h0 = (r >> 3) * 32;     // h0 <= 384
    const float* __restrict__ src = mat ? Y : X;
    const int wcol = mat ? DIM : 0;
    const int kb = kh * 200;

    float a00 = 0.f, a01 = 0.f, a10 = 0.f, a11 = 0.f;    // [n r][h c]

    for (int kc = 0; kc < 200; kc += 100) {
        __syncthreads();
        // stage A: rows n0..n0+63, 100 k -> As[k][n]
        for (int idx = t; idx < 1600; idx += 512) {
            const int n = idx / 25, kq = idx % 25;
            float4 v = *(const float4*)(src + (size_t)(n0 + n) * DIM + kb + kc + 4 * kq);
            float* d = As + (4 * kq) * 64 + n;
            d[0] = v.x; d[64] = v.y; d[128] = v.z; d[192] = v.w;
        }
        // stage B: W1 rows h0..h0+31 (clamped), cols wcol+kb+kc -> Bs[k][h]
        for (int idx = t; idx < 800; idx += 512) {
            const int h = idx / 25, kq = idx % 25;
            int hr = h0 + h; if (hr > HID - 1) hr = HID - 1;
            float4 v = *(const float4*)(W1 + (size_t)hr * (2 * DIM) + wcol + kb + kc + 4 * kq);
            float* d = Bs + (4 * kq) * 32 + h;
            d[0] = v.x; d[32] = v.y; d[64] = v.z; d[96] = v.w;
        }
        __syncthreads();
#pragma unroll 4
        for (int k = 0; k < 100; k++) {
            float2 av = *(const float2*)(As + k * 64 + 2 * ty);   // 4 addr/wave
            float2 bv = *(const float2*)(Bs + k * 32 + 2 * tx);   // 16 addr/wave
            a00 = fmaf(av.x, bv.x, a00);
            a01 = fmaf(av.x, bv.y, a01);
            a10 = fmaf(av.y, bv.x, a10);
            a11 = fmaf(av.y, bv.y, a11);
        }
    }

    const int hA = h0 + 2 * tx, hB = hA + 1;   // <= 415, store-guarded
    const int nA = n0 + 2 * ty, nB = nA + 1;
    if (mat == 0) {
        if (hA < HID) {
            float* p = hxT8 + (size_t)(hA >> 3) * 4096 + (hA & 7);
            atomicAdd(p + nA * 8, a00);
            atomicAdd(p + nB * 8, a10);
        }
        if (hB < HID) {
            float* p = hxT8 + (size_t)(hB >> 3) * 4096 + (hB & 7);
            atomicAdd(p + nA * 8, a01);
            atomicAdd(p + nB * 8, a11);
        }
    } else {
        float bv0 = 0.f, bv1 = 0.f;
        if (kh == 0) {                       // fold b1 exactly once per (n,h)
            bv0 = b1[hA < HID ? hA : HID - 1];
            bv1 = b1[hB < HID ? hB : HID - 1];
        }
        if (hA < HID) {
            atomicAdd(hyb + (size_t)nA * HID + hA, a00 + bv0);
            atomicAdd(hyb + (size_t)nB * HID + hA, a10 + bv0);
        }
        if (hB < HID) {
            atomicAdd(hyb + (size_t)nA * HID + hB, a01 + bv1);
            atomicAdd(hyb + (size_t)nB * HID + hB, a11 + bv1);
        }
    }
}

// ---------------- K2: pair scores + fused final ----------------
// grid (8 jx, 128 ig), block 256 (4 waves): grp = wave>>1 (2 i), half = wave&1.
__global__ __launch_bounds__(256) void club_pair_kernel(
    const float* __restrict__ hxT8, const float* __restrict__ hyb,
    const float* __restrict__ W2, const float* __restrict__ b2,
    double* __restrict__ expsum, double* __restrict__ tsum,
    double* __restrict__ diagT, unsigned int* __restrict__ counter,
    float* __restrict__ out)
{
    __shared__ __align__(16) float As4[4 * 400];   // hyb rows ig*4..+4 (b1 inside)
    __shared__ __align__(16) float W2s[400];
    __shared__ float Cs[2][2][64];                 // half-1 partials per grp
    __shared__ double Rs[3 * 256];
    __shared__ bool isLast;

    const int t    = threadIdx.x;
    const int lane = t & 63;
    const int wave = __builtin_amdgcn_readfirstlane(t >> 6);
    const int grp  = wave >> 1, half = wave & 1;
    const int jx   = blockIdx.x, ig = blockIdx.y;
    const int j    = jx * 64 + lane;

    for (int idx = t; idx < 400; idx += 256) {
        const int il = idx / 100, q = idx % 100;
        *(float4*)(As4 + il * 400 + 4 * q) =
            *(const float4*)(hyb + (size_t)(ig * 4 + il) * HID + 4 * q);
    }
    if (t < 100) *(float4*)(W2s + 4 * t) = *(const float4*)(W2 + 4 * t);
    __syncthreads();

    const float* __restrict__ Bp  = hxT8 + ((size_t)(half * 25) * NSAMP + j) * 8;
    const float* __restrict__ ap0 = As4 + (grp * 2) * 400 + half * 200;
    const float* __restrict__ ap1 = ap0 + 400;
    const float* __restrict__ wp  = W2s + half * 200;

    float acc0 = 0.f, acc1 = 0.f;
    float4 c0 = *(const float4*)(Bp);          // prefetched current group
    float4 c1 = *(const float4*)(Bp + 4);

#pragma unroll 2
    for (int g = 0; g < 25; g++) {
        float4 p0, p1;                          // prefetch next group
        if (g < 24) {
            p0 = *(const float4*)(Bp + (size_t)(g + 1) * 4096);
            p1 = *(const float4*)(Bp + (size_t)(g + 1) * 4096 + 4);
        }
        float4 w0 = *(const float4*)(wp + 8 * g);       // broadcast b128
        float4 w1 = *(const float4*)(wp + 8 * g + 4);
        float4 a0 = *(const float4*)(ap0 + 8 * g);
        float4 a1 = *(const float4*)(ap0 + 8 * g + 4);
        float4 d0 = *(const float4*)(ap1 + 8 * g);
        float4 d1 = *(const float4*)(ap1 + 8 * g + 4);
        acc0 = fmaf(fmaxf(a0.x + c0.x, 0.f), w0.x, acc0);
        acc0 = fmaf(fmaxf(a0.y + c0.y, 0.f), w0.y, acc0);
        acc0 = fmaf(fmaxf(a0.z + c0.z, 0.f), w0.z, acc0);
        acc0 = fmaf(fmaxf(a0.w + c0.w, 0.f), w0.w, acc0);
        acc0 = fmaf(fmaxf(a1.x + c1.x, 0.f), w1.x, acc0);
        acc0 = fmaf(fmaxf(a1.y + c1.y, 0.f), w1.y, acc0);
        acc0 = fmaf(fmaxf(a1.z + c1.z, 0.f), w1.z, acc0);
        acc0 = fmaf(fmaxf(a1.w + c1.w, 0.f), w1.w, acc0);
        acc1 = fmaf(fmaxf(d0.x + c0.x, 0.f), w0.x, acc1);
        acc1 = fmaf(fmaxf(d0.y + c0.y, 0.f), w0.y, acc1);
        acc1 = fmaf(fmaxf(d0.z + c0.z, 0.f), w0.z, acc1);
        acc1 = fmaf(fmaxf(d0.w + c0.w, 0.f), w0.w, acc1);
        acc1 = fmaf(fmaxf(d1.x + c1.x, 0.f), w1.x, acc1);
        acc1 = fmaf(fmaxf(d1.y + c1.y, 0.f), w1.y, acc1);
        acc1 = fmaf(fmaxf(d1.z + c1.z, 0.f), w1.z, acc1);
        acc1 = fmaf(fmaxf(d1.w + c1.w, 0.f), w1.w, acc1);
        c0 = p0; c1 = p1;
    }

    if (half == 1) { Cs[grp][0][lane] = acc0; Cs[grp][1][lane] = acc1; }
    __syncthreads();

    if (half == 0) {
        const float bb2 = b2[0];
#pragma unroll
        for (int r = 0; r < 2; r++) {
            const int i = ig * 4 + grp * 2 + r;
            float s  = (r ? acc1 : acc0) + Cs[grp][r][lane] + bb2;
            float es = expf(s);
            float T  = log1pf(es);               // softplus
            if (j == i) diagT[i] = (double)T;    // T0[i]
            double eD = 1.0 + (double)es;        // exp(softplus(s)) exactly
            double tD = (double)T;
            for (int off = 32; off > 0; off >>= 1) {
                eD += __shfl_down(eD, off);
                tD += __shfl_down(tD, off);
            }
            if (lane == 0) {
                expsum[i * 8 + jx] = eD;
                tsum  [i * 8 + jx] = tD;
            }
        }
    }

    // ---- last-block final reduction (R8-validated pattern) ----
    __threadfence();
    __syncthreads();
    if (t == 0) isLast = (atomicAdd(counter, 1u) == 1023u);
    __syncthreads();
    if (!isLast) return;
    __threadfence();

    double lse = 0.0, tsm = 0.0, dg = 0.0;
    for (int i = t; i < NSAMP; i += 256) {
        double es = 0.0, ts = 0.0;
#pragma unroll
        for (int bq = 0; bq < 8; bq++) { es += expsum[i * 8 + bq]; ts += tsum[i * 8 + bq]; }
        lse += log(es);
        tsm += ts;
        dg  += diagT[i];
    }
    Rs[t] = lse; Rs[256 + t] = tsm; Rs[512 + t] = dg;
    __syncthreads();
    for (int off = 128; off > 0; off >>= 1) {
        if (t < off) {
            Rs[t]       += Rs[t + off];
            Rs[256 + t] += Rs[256 + t + off];
            Rs[512 + t] += Rs[512 + t + off];
        }
        __syncthreads();
    }
    if (t == 0) {
        double t0m  = Rs[512] / 512.0;
        double lsem = Rs[0]   / 512.0;
        double t1m  = Rs[256] / (512.0 * 512.0);
        out[0] = (float)(t0m - (lsem - log(512.0)));   // lower bound
        out[1] = (float)(t0m - t1m);                   // upper bound
    }
}

extern "C" void kernel_launch(void* const* d_in, const int* in_sizes, int n_in,
                              void* d_out, int out_size, void* d_ws, size_t ws_size,
                              hipStream_t stream) {
    const float* X  = (const float*)d_in[0];
    const float* Y  = (const float*)d_in[1];
    const float* W1 = (const float*)d_in[2];
    const float* b1 = (const float*)d_in[3];
    const float* W2 = (const float*)d_in[4];
    const float* b2 = (const float*)d_in[5];
    float* out = (float*)d_out;

    char* ws = (char*)d_ws;
    float*        hxT8    = (float*) (ws);               // 50*512*8*4 = 819200
    float*        hyb     = (float*) (ws +  819200);     // 512*400*4  = 819200
    double*       expsum  = (double*)(ws + 1638400);     // 512*8*8 = 32768
    double*       tsum    = (double*)(ws + 1671168);     // 32768
    double*       diagT   = (double*)(ws + 1703936);     // 4096
    unsigned int* counter = (unsigned int*)(ws + 1708032);

    hipMemsetAsync(ws, 0, 1638400, stream);              // zero atomic targets
    club_gemm_kernel<<<dim3(416),    512, 0, stream>>>(X, Y, W1, b1, hxT8, hyb, counter);
    club_pair_kernel<<<dim3(8, 128), 256, 0, stream>>>(hxT8, hyb, W2, b2,
                                                       expsum, tsum, diagT, counter, out);
}

// Round 11
// 116.203 us; speedup vs baseline: 1.4744x; 1.4744x over previous
//
#include <hip/hip_runtime.h>
#include <math.h>

// CLUB_NCE: N=512, D=400, H=400.  memset + K1 + K2 + K3 (R7 skeleton).
// LAW (R6-R10): kernels here are bound by dependent-load round-trips per wave,
// not occupancy. K2 rebuilt as mega-batch MLP: 20 independent dwordx4 per
// chunk into registers (launch_bounds(256,2) -> 256 VGPR cap), one wait,
// 480 VALU ops -> 5 round-trips per wave instead of ~50.
// K1 : (R7-proven) 848 blocks x 256 thr, k-split 2, LDS lane-operand,
//      4 uniform scalar rows/thread; k-halves combined via fp32 atomicAdd
//      (2 addends, commutative, bit-exact) into memset-zeroed buffers.
//      mat0 -> hxT8[h/8][j][h%8] (oct layout), mat1 -> hyb[n][h] (+b1 in kh0).
// K2 : pair scores, grid (8 jx, 64 ib) x 256 thr, wave = 2 i x 64 j x 400 h.
//      B from hxT8 oct layout; A rows + W2 via uniform s_loads (batched by
//      the compiler inside each chunk). Fused softplus + fp64 wave reduce.
// K3 : fp64 logsumexp assembly -> (lower, upper).

#define NSAMP 512
#define DIM 400
#define HID 400

// ---------------- K1 (R7-proven) ----------------
// blocks 0..399   : mat0: kh=b&1, bx=(b>>1)&7 -> j0=bx*64 (lane), by=b>>4 (0..24)
// blocks 400..847 : mat1: bb=b-400: kh=bb&1, bx=(bb>>1)&31 -> n0=bx*16, by=bb>>6 (0..6)
__global__ __launch_bounds__(256) void club_gemm_kernel(
    const float* __restrict__ X, const float* __restrict__ Y,
    const float* __restrict__ W1, const float* __restrict__ b1,
    float* __restrict__ hxT8, float* __restrict__ hyb)
{
    __shared__ __align__(16) float Ls[64 * 204];   // 52224 B -> 3 blocks/CU
    const int t    = threadIdx.x;
    const int lane = t & 63;
    const int wave = __builtin_amdgcn_readfirstlane(t >> 6);
    const int b    = blockIdx.x;

    const float* __restrict__ Lbase;   // lane-dim matrix (LDS-staged)
    const float* __restrict__ Sbase;   // scalar-dim matrix (uniform s_load)
    int Lstride, Lcol0, Lrow0, Lrowmax, Sstride, srow_base;
    int kh, mat;

    if (b < 400) {                    // mat0: hx
        mat = 0; kh = b & 1;
        const int bx = (b >> 1) & 7, by = b >> 4;
        Lbase = X;  Lstride = DIM;     Lcol0 = 0;   Lrow0 = bx * 64; Lrowmax = NSAMP - 1;
        Sbase = W1; Sstride = 2 * DIM;
        srow_base = by * 16 + wave * 4;             // h rows, max 399
    } else {                          // mat1: hy (+b1)
        mat = 1;
        const int bb = b - 400; kh = bb & 1;
        const int bx = (bb >> 1) & 31, by = bb >> 6;
        Lbase = W1; Lstride = 2 * DIM; Lcol0 = DIM; Lrow0 = by * 64; Lrowmax = HID - 1;
        Sbase = Y;  Sstride = DIM;
        srow_base = bx * 16 + wave * 4;             // n rows, max 511
    }
    const int kc0 = kh * 200;

    // stage lane-dim tile: 64 rows x 200 k -> Ls, coalesced float4
    for (int idx = t; idx < 3200; idx += 256) {
        int row = idx / 50, q = idx % 50;
        int r = Lrow0 + row; if (r > Lrowmax) r = Lrowmax;
        float4 v = *(const float4*)(Lbase + (size_t)r * Lstride + Lcol0 + kc0 + 4 * q);
        *(float4*)(Ls + row * 204 + 4 * q) = v;
    }
    __syncthreads();

    float acc[4] = {0.f, 0.f, 0.f, 0.f};
#pragma unroll 2
    for (int k4 = 0; k4 < 50; k4++) {
        float4 xv = *(const float4*)(Ls + lane * 204 + 4 * k4);
#pragma unroll
        for (int c = 0; c < 4; c++) {
            float4 wv = *(const float4*)(Sbase + (size_t)(srow_base + c) * Sstride + kc0 + 4 * k4);
            acc[c] = fmaf(xv.x, wv.x, acc[c]);
            acc[c] = fmaf(xv.y, wv.y, acc[c]);
            acc[c] = fmaf(xv.z, wv.z, acc[c]);
            acc[c] = fmaf(xv.w, wv.w, acc[c]);
        }
    }

    if (mat == 0) {
        // hxT8[h>>3][j][h&7], h = srow_base+c (quad-aligned), j = Lrow0+lane
        const int j = Lrow0 + lane;
        float* __restrict__ base =
            hxT8 + (size_t)(srow_base >> 3) * 4096 + (size_t)j * 8 + (srow_base & 4);
#pragma unroll
        for (int c = 0; c < 4; c++)
            atomicAdd(base + c, acc[c]);
    } else {
        const int h = Lrow0 + lane;
        if (h < HID) {
            if (kh == 0) {
                float bv = b1[h];
#pragma unroll
                for (int c = 0; c < 4; c++) acc[c] += bv;
            }
#pragma unroll
            for (int c = 0; c < 4; c++)
                atomicAdd(hyb + (size_t)(srow_base + c) * HID + h, acc[c]);
        }
    }
}

// ---------------- K2: pair scores, mega-batch MLP ----------------
// grid (8 jx, 64 ib), block 256 (4 waves). wave = 2 i-rows; lane = j.
// 5 chunks x 10 oct-groups: 20 independent dwordx4 -> regs, then 480 VALU.
__global__ __launch_bounds__(256, 2) void club_pair_kernel(
    const float* __restrict__ hxT8, const float* __restrict__ hyb,
    const float* __restrict__ W2, const float* __restrict__ b2,
    double* __restrict__ expsum, double* __restrict__ tsum,
    double* __restrict__ diagT)
{
    const int t    = threadIdx.x;
    const int lane = t & 63;
    const int wave = __builtin_amdgcn_readfirstlane(t >> 6);
    const int jx   = blockIdx.x;
    const int j    = jx * 64 + lane;
    const int i0   = (blockIdx.y * 4 + wave) * 2;   // uniform, 0..510

    const float* __restrict__ Bp = hxT8 + (size_t)j * 8;
    const float* __restrict__ A0 = hyb + (size_t)i0 * HID;
    const float* __restrict__ A1 = A0 + HID;

    float acc0 = 0.f, acc1 = 0.f;

    for (int c = 0; c < 5; c++) {                   // 5 dependent round-trips
        const int g0 = c * 10;
        float4 B[20];                               // 80 h values in 80 VGPRs
#pragma unroll
        for (int u = 0; u < 10; u++) {
            const float* __restrict__ p = Bp + (size_t)(g0 + u) * 4096;
            B[2 * u]     = *(const float4*)(p);
            B[2 * u + 1] = *(const float4*)(p + 4);
        }
#pragma unroll
        for (int u = 0; u < 10; u++) {
            const int h = (g0 + u) * 8;
            float4 w0 = *(const float4*)(W2 + h);       // uniform s_loads
            float4 w1 = *(const float4*)(W2 + h + 4);
            float4 a0 = *(const float4*)(A0 + h);
            float4 a1 = *(const float4*)(A0 + h + 4);
            float4 d0 = *(const float4*)(A1 + h);
            float4 d1 = *(const float4*)(A1 + h + 4);
            float4 b0 = B[2 * u], b1v = B[2 * u + 1];
            acc0 = fmaf(fmaxf(a0.x + b0.x, 0.f), w0.x, acc0);
            acc0 = fmaf(fmaxf(a0.y + b0.y, 0.f), w0.y, acc0);
            acc0 = fmaf(fmaxf(a0.z + b0.z, 0.f), w0.z, acc0);
            acc0 = fmaf(fmaxf(a0.w + b0.w, 0.f), w0.w, acc0);
            acc0 = fmaf(fmaxf(a1.x + b1v.x, 0.f), w1.x, acc0);
            acc0 = fmaf(fmaxf(a1.y + b1v.y, 0.f), w1.y, acc0);
            acc0 = fmaf(fmaxf(a1.z + b1v.z, 0.f), w1.z, acc0);
            acc0 = fmaf(fmaxf(a1.w + b1v.w, 0.f), w1.w, acc0);
            acc1 = fmaf(fmaxf(d0.x + b0.x, 0.f), w0.x, acc1);
            acc1 = fmaf(fmaxf(d0.y + b0.y, 0.f), w0.y, acc1);
            acc1 = fmaf(fmaxf(d0.z + b0.z, 0.f), w0.z, acc1);
            acc1 = fmaf(fmaxf(d0.w + b0.w, 0.f), w0.w, acc1);
            acc1 = fmaf(fmaxf(d1.x + b1v.x, 0.f), w1.x, acc1);
            acc1 = fmaf(fmaxf(d1.y + b1v.y, 0.f), w1.y, acc1);
            acc1 = fmaf(fmaxf(d1.z + b1v.z, 0.f), w1.z, acc1);
            acc1 = fmaf(fmaxf(d1.w + b1v.w, 0.f), w1.w, acc1);
        }
    }

    // epilogue: softplus + fp64 reduction over the 64 j-lanes, per i-row
    const float bb2 = b2[0];
#pragma unroll
    for (int r = 0; r < 2; r++) {
        const int i = i0 + r;
        float s  = (r ? acc1 : acc0) + bb2;
        float es = expf(s);
        float T  = log1pf(es);               // softplus
        if (j == i) diagT[i] = (double)T;    // T0[i]
        double eD = 1.0 + (double)es;        // exp(softplus(s)) exactly
        double tD = (double)T;
        for (int off = 32; off > 0; off >>= 1) {
            eD += __shfl_down(eD, off);
            tD += __shfl_down(tD, off);
        }
        if (lane == 0) {
            expsum[i * 8 + jx] = eD;
            tsum  [i * 8 + jx] = tD;
        }
    }
}

// ---------------- K3: final assembly ----------------
__global__ __launch_bounds__(512) void club_final_kernel(
    const double* __restrict__ expsum, const double* __restrict__ tsum,
    const double* __restrict__ diagT, float* __restrict__ out)
{
    __shared__ double sh[3 * 512];
    const int t = threadIdx.x;   // = i
    double es = 0.0, ts = 0.0;
#pragma unroll
    for (int b = 0; b < 8; b++) { es += expsum[t * 8 + b]; ts += tsum[t * 8 + b]; }
    sh[t] = log(es); sh[512 + t] = ts; sh[1024 + t] = diagT[t];
    __syncthreads();
    for (int off = 256; off > 0; off >>= 1) {
        if (t < off) {
            sh[t]        += sh[t + off];
            sh[512 + t]  += sh[512 + t + off];
            sh[1024 + t] += sh[1024 + t + off];
        }
        __syncthreads();
    }
    if (t == 0) {
        double t0m  = sh[1024] / 512.0;
        double lsem = sh[0]    / 512.0;
        double t1m  = sh[512]  / (512.0 * 512.0);
        out[0] = (float)(t0m - (lsem - log(512.0)));
        out[1] = (float)(t0m - t1m);
    }
}

extern "C" void kernel_launch(void* const* d_in, const int* in_sizes, int n_in,
                              void* d_out, int out_size, void* d_ws, size_t ws_size,
                              hipStream_t stream) {
    const float* X  = (const float*)d_in[0];
    const float* Y  = (const float*)d_in[1];
    const float* W1 = (const float*)d_in[2];
    const float* b1 = (const float*)d_in[3];
    const float* W2 = (const float*)d_in[4];
    const float* b2 = (const float*)d_in[5];
    float* out = (float*)d_out;

    char* ws = (char*)d_ws;
    float*  hxT8   = (float*) (ws);                 // 50*512*8*4 = 819200
    float*  hyb    = (float*) (ws +  819200);       // 512*400*4  = 819200
    double* expsum = (double*)(ws + 1638400);       // 512*8*8    = 32768
    double* tsum   = (double*)(ws + 1671168);       // 32768
    double* diagT  = (double*)(ws + 1703936);       // 4096

    hipMemsetAsync(ws, 0, 1638400, stream);         // zero atomic targets

    club_gemm_kernel <<<dim3(848),   256, 0, stream>>>(X, Y, W1, b1, hxT8, hyb);
    club_pair_kernel <<<dim3(8, 64), 256, 0, stream>>>(hxT8, hyb, W2, b2,
                                                       expsum, tsum, diagT);
    club_final_kernel<<<1, 512, 0, stream>>>(expsum, tsum, diagT, out);
}